// Round 5
// baseline (154.259 us; speedup 1.0000x reference)
//
#include <hip/hip_runtime.h>

// FeatureAggregation via MFMA bf16 (fp32 accumulate).
// R4 compute structure (verified) + 2-tile-per-block software pipeline:
// tile k+1's HBM loads are issued at the start of tile k's compute phase,
// converted in two chunks mid-compute, written to LDS after tile k's LDS
// reads complete. Hides the ~900cy scattered-load latency under MFMA work.
// B=8, C=64, N=16384, K=16 but only k<3 used (reference quirk).

typedef __attribute__((ext_vector_type(8))) short short8v;
typedef __attribute__((ext_vector_type(4))) float f32x4;

#define BN_EPS 1e-5f

__device__ __forceinline__ unsigned short f2bf(float f) {
    union { float f; unsigned u; } U; U.f = f;
    unsigned r = U.u + 0x7FFFu + ((U.u >> 16) & 1u);   // RNE; inputs finite
    return (unsigned short)(r >> 16);
}

union FragU { uint4 u; short8v s; uint2 h[2]; };

// ---- d_ws layout (bytes) ----
//     0 : W1 frags uint4[1536]  (frag = ct*3+ks, ct 0..7, ks 0..2; zero-pad k>=68)
// 24576 : W2 frags uint4[1024]  (frag = ct*4+ks, ct 0..3, ks 0..3)
// 40960 : W3 frags uint4[512]   (frag = ct*2+ks, ct 0..3, ks 0..1)
// 49152 : s1[128]  49664 : t1[128]
// 50176 : s2[64]   50432 : t2[64]
// 50688 : s3[64]   50944 : t3[64]

__global__ __launch_bounds__(256) void fa_pack(
    const float* __restrict__ W1, const float* __restrict__ g1, const float* __restrict__ b1,
    const float* __restrict__ m1, const float* __restrict__ v1,
    const float* __restrict__ W2, const float* __restrict__ g2, const float* __restrict__ b2,
    const float* __restrict__ m2, const float* __restrict__ v2,
    const float* __restrict__ W3, const float* __restrict__ g3, const float* __restrict__ b3,
    const float* __restrict__ m3, const float* __restrict__ v3,
    char* __restrict__ ws)
{
    const int id = blockIdx.x * 256 + threadIdx.x;
    if (id < 1536) {                       // W1: 96(K,zero-padded) x 128
        const int lane = id & 63, frag = id >> 6;
        const int ct = frag / 3, ks = frag - 3 * ct;
        const int o  = ct * 16 + (lane & 15);
        const int kb = ks * 32 + (lane >> 4) * 8;
        unsigned short h[8];
        #pragma unroll
        for (int j = 0; j < 8; ++j) {
            const int k = kb + j;
            h[j] = (k < 68) ? f2bf(W1[o * 68 + k]) : (unsigned short)0;
        }
        uint4 pk;
        pk.x = h[0] | (h[1] << 16); pk.y = h[2] | (h[3] << 16);
        pk.z = h[4] | (h[5] << 16); pk.w = h[6] | (h[7] << 16);
        ((uint4*)ws)[id] = pk;
    } else if (id < 2560) {                // W2: 128 x 64
        const int i2 = id - 1536;
        const int lane = i2 & 63, frag = i2 >> 6;
        const int o  = (frag >> 2) * 16 + (lane & 15);
        const int kb = (frag & 3) * 32 + (lane >> 4) * 8;
        unsigned short h[8];
        #pragma unroll
        for (int j = 0; j < 8; ++j) h[j] = f2bf(W2[o * 128 + kb + j]);
        uint4 pk;
        pk.x = h[0] | (h[1] << 16); pk.y = h[2] | (h[3] << 16);
        pk.z = h[4] | (h[5] << 16); pk.w = h[6] | (h[7] << 16);
        ((uint4*)(ws + 24576))[i2] = pk;
    } else if (id < 3072) {                // W3: 64 x 64
        const int i3 = id - 2560;
        const int lane = i3 & 63, frag = i3 >> 6;
        const int o  = (frag >> 1) * 16 + (lane & 15);
        const int kb = (frag & 1) * 32 + (lane >> 4) * 8;
        unsigned short h[8];
        #pragma unroll
        for (int j = 0; j < 8; ++j) h[j] = f2bf(W3[o * 64 + kb + j]);
        uint4 pk;
        pk.x = h[0] | (h[1] << 16); pk.y = h[2] | (h[3] << 16);
        pk.z = h[4] | (h[5] << 16); pk.w = h[6] | (h[7] << 16);
        ((uint4*)(ws + 40960))[i3] = pk;
    } else if (id < 3200) {                // BN fold L1
        const int o = id - 3072;
        const float s = g1[o] * rsqrtf(v1[o] + BN_EPS);
        ((float*)(ws + 49152))[o] = s;
        ((float*)(ws + 49664))[o] = b1[o] - m1[o] * s;
    } else if (id < 3264) {                // BN fold L2
        const int o = id - 3200;
        const float s = g2[o] * rsqrtf(v2[o] + BN_EPS);
        ((float*)(ws + 50176))[o] = s;
        ((float*)(ws + 50432))[o] = b2[o] - m2[o] * s;
    } else if (id < 3328) {                // BN fold L3
        const int o = id - 3264;
        const float s = g3[o] * rsqrtf(v3[o] + BN_EPS);
        ((float*)(ws + 50688))[o] = s;
        ((float*)(ws + 50944))[o] = b3[o] - m3[o] * s;
    }
}

__global__ __launch_bounds__(128, 3) void fa_mfma(
    const float* __restrict__ src, const float* __restrict__ tgt,
    const float* __restrict__ feat,
    const char* __restrict__ ws, float* __restrict__ out)
{
    constexpr int N = 16384;
    // ONE shared buffer, overlaid views (phases separated by barriers):
    //   X0 view: 96 rows x stride 72 (input staging; later layer-2 output X2)
    //   X1 view: 96 rows x stride 136 (layer-1 output)
    __shared__ unsigned short SM[96 * 136];   // 26112 B -> 6 blocks/CU
    #define X0V(r, c) SM[(r) * 72 + (c)]
    #define X1V(r, c) SM[(r) * 136 + (c)]

    const int t  = threadIdx.x;
    const int T0 = blockIdx.x * 2;              // 2 consecutive tiles per block
    const int b0  = T0 >> 9;
    const int n00 = (T0 & 511) << 5;
    const int b1t  = (T0 + 1) >> 9;             // same batch as b0 (T0 even)
    const int n01 = ((T0 + 1) & 511) << 5;

    const int p  = t & 31;
    const int cg = t >> 5;                      // 0..3
    const bool rel = t < 96;
    const int rp = t & 31, rk = t >> 5;         // rel thread coords (t<96)

    const int w = t >> 6, lane = t & 63, lo = lane & 15, hi = lane >> 4;

    const uint4*  w1f = (const uint4*)ws;
    const uint4*  w2f = (const uint4*)(ws + 24576);
    const uint4*  w3f = (const uint4*)(ws + 40960);
    const float*  s1w = (const float*)(ws + 49152);
    const float*  t1w = (const float*)(ws + 49664);
    const float*  s2w = (const float*)(ws + 50176);
    const float*  t2w = (const float*)(ws + 50432);
    const float*  s3w = (const float*)(ws + 50688);
    const float*  t3w = (const float*)(ws + 50944);

    // ================= tile0: full staging =================
    {
        float4 fr[16];
        #pragma unroll
        for (int it = 0; it < 4; ++it) {
            const float* fp = feat + ((size_t)(b0 * 64 + it * 16 + cg * 4) * N + n00 + p) * 16;
            #pragma unroll
            for (int q = 0; q < 4; ++q)
                fr[it * 4 + q] = *(const float4*)(fp + (size_t)q * N * 16);
        }
        float rs0 = 0, rs1 = 0, rs2 = 0, rt0 = 0, rt1 = 0, rt2 = 0;
        if (rel) {
            const int n = n00 + rp;
            rs0 = src[((b0 * 3 + 0) * N + n) * 16 + rk]; rt0 = tgt[(b0 * 3 + 0) * N + n];
            rs1 = src[((b0 * 3 + 1) * N + n) * 16 + rk]; rt1 = tgt[(b0 * 3 + 1) * N + n];
            rs2 = src[((b0 * 3 + 2) * N + n) * 16 + rk]; rt2 = tgt[(b0 * 3 + 2) * N + n];
        }
        #pragma unroll
        for (int it = 0; it < 4; ++it) {
            const int c0 = it * 16 + cg * 4;
            const float4 f0 = fr[it * 4 + 0], f1 = fr[it * 4 + 1];
            const float4 f2 = fr[it * 4 + 2], f3 = fr[it * 4 + 3];
            uint2 u0, u1, u2;
            u0.x = f2bf(f0.x) | (f2bf(f1.x) << 16); u0.y = f2bf(f2.x) | (f2bf(f3.x) << 16);
            u1.x = f2bf(f0.y) | (f2bf(f1.y) << 16); u1.y = f2bf(f2.y) | (f2bf(f3.y) << 16);
            u2.x = f2bf(f0.z) | (f2bf(f1.z) << 16); u2.y = f2bf(f2.z) | (f2bf(f3.z) << 16);
            *(uint2*)&X0V(0 * 32 + p, c0) = u0;
            *(uint2*)&X0V(1 * 32 + p, c0) = u1;
            *(uint2*)&X0V(2 * 32 + p, c0) = u2;
        }
        if (rel) {
            const float d0 = rs0 - rt0, d1 = rs1 - rt1, d2 = rs2 - rt2;
            const float ds = d0 * d0 + d1 * d1 + d2 * d2;
            uint2 wr; wr.x = f2bf(d0) | (f2bf(d1) << 16); wr.y = f2bf(d2) | (f2bf(ds) << 16);
            *(uint2*)&X0V(rk * 32 + rp, 64) = wr;
        }
    }
    __syncthreads();   // B1: tile0 X0 staged

    // ---- a1 fragments tile0 ----
    short8v a1[3][3];
    #pragma unroll
    for (int k = 0; k < 3; ++k) {
        const int row = k * 32 + w * 16 + lo;
        a1[k][0] = *(const short8v*)&X0V(row, hi * 8);
        a1[k][1] = *(const short8v*)&X0V(row, 32 + hi * 8);
        FragU U; U.u.x = 0; U.u.y = 0; U.u.z = 0; U.u.w = 0;
        if (hi == 0) U.h[0] = *(const uint2*)&X0V(row, 64);
        a1[k][2] = U.s;
    }
    __syncthreads();   // B2: X0 dead, X1 region free

    // ---- tile1 prefetch chunk A (it=0,1) + relation loads ----
    float4 frA[8];
    #pragma unroll
    for (int it = 0; it < 2; ++it) {
        const float* fp = feat + ((size_t)(b1t * 64 + it * 16 + cg * 4) * N + n01 + p) * 16;
        #pragma unroll
        for (int q = 0; q < 4; ++q)
            frA[it * 4 + q] = *(const float4*)(fp + (size_t)q * N * 16);
    }
    float prs0 = 0, prs1 = 0, prs2 = 0, prt0 = 0, prt1 = 0, prt2 = 0;
    if (rel) {
        const int n = n01 + rp;
        prs0 = src[((b1t * 3 + 0) * N + n) * 16 + rk]; prt0 = tgt[(b1t * 3 + 0) * N + n];
        prs1 = src[((b1t * 3 + 1) * N + n) * 16 + rk]; prt1 = tgt[(b1t * 3 + 1) * N + n];
        prs2 = src[((b1t * 3 + 2) * N + n) * 16 + rk]; prt2 = tgt[(b1t * 3 + 2) * N + n];
    }

    // ---- layer 1 tile0 : K=96 (68 real) -> 128, write X1 ----
    #pragma unroll 2
    for (int ct = 0; ct < 8; ++ct) {
        FragU B0, B1, B2;
        B0.u = w1f[(ct * 3 + 0) * 64 + lane];
        B1.u = w1f[(ct * 3 + 1) * 64 + lane];
        B2.u = w1f[(ct * 3 + 2) * 64 + lane];
        const float sc = s1w[ct * 16 + lo];
        const float tb = t1w[ct * 16 + lo];
        #pragma unroll
        for (int k = 0; k < 3; ++k) {
            f32x4 acc = {0.f, 0.f, 0.f, 0.f};
            acc = __builtin_amdgcn_mfma_f32_16x16x32_bf16(a1[k][0], B0.s, acc, 0, 0, 0);
            acc = __builtin_amdgcn_mfma_f32_16x16x32_bf16(a1[k][1], B1.s, acc, 0, 0, 0);
            acc = __builtin_amdgcn_mfma_f32_16x16x32_bf16(a1[k][2], B2.s, acc, 0, 0, 0);
            const int rb = k * 32 + w * 16 + 4 * hi;
            #pragma unroll
            for (int j = 0; j < 4; ++j) {
                const float y = fmaxf(fmaf(sc, acc[j], tb), 0.f);
                X1V(rb + j, ct * 16 + lo) = f2bf(y);
            }
        }
    }

    // ---- convert chunk A -> pk[0..5]; issue chunk B (it=2,3) ----
    uint2 pk[12];
    #pragma unroll
    for (int it = 0; it < 2; ++it) {
        const float4 f0 = frA[it * 4 + 0], f1 = frA[it * 4 + 1];
        const float4 f2 = frA[it * 4 + 2], f3 = frA[it * 4 + 3];
        pk[it * 3 + 0].x = f2bf(f0.x) | (f2bf(f1.x) << 16);
        pk[it * 3 + 0].y = f2bf(f2.x) | (f2bf(f3.x) << 16);
        pk[it * 3 + 1].x = f2bf(f0.y) | (f2bf(f1.y) << 16);
        pk[it * 3 + 1].y = f2bf(f2.y) | (f2bf(f3.y) << 16);
        pk[it * 3 + 2].x = f2bf(f0.z) | (f2bf(f1.z) << 16);
        pk[it * 3 + 2].y = f2bf(f2.z) | (f2bf(f3.z) << 16);
    }
    float4 frB[8];
    #pragma unroll
    for (int it = 0; it < 2; ++it) {
        const float* fp = feat + ((size_t)(b1t * 64 + (it + 2) * 16 + cg * 4) * N + n01 + p) * 16;
        #pragma unroll
        for (int q = 0; q < 4; ++q)
            frB[it * 4 + q] = *(const float4*)(fp + (size_t)q * N * 16);
    }

    // ---- a2 fragments tile0 ----
    short8v a2[3][4];
    #pragma unroll
    for (int k = 0; k < 3; ++k) {
        const int row = k * 32 + w * 16 + lo;
        #pragma unroll
        for (int ks = 0; ks < 4; ++ks)
            a2[k][ks] = *(const short8v*)&X1V(row, ks * 32 + hi * 8);
    }
    __syncthreads();   // B3: X1 dead

    // ---- layer 2 tile0 : K=128 -> 64, write X2 (X0 view) ----
    #pragma unroll 2
    for (int ct = 0; ct < 4; ++ct) {
        FragU B0, B1, B2, B3;
        B0.u = w2f[(ct * 4 + 0) * 64 + lane];
        B1.u = w2f[(ct * 4 + 1) * 64 + lane];
        B2.u = w2f[(ct * 4 + 2) * 64 + lane];
        B3.u = w2f[(ct * 4 + 3) * 64 + lane];
        const float sc = s2w[ct * 16 + lo];
        const float tb = t2w[ct * 16 + lo];
        #pragma unroll
        for (int k = 0; k < 3; ++k) {
            f32x4 acc = {0.f, 0.f, 0.f, 0.f};
            acc = __builtin_amdgcn_mfma_f32_16x16x32_bf16(a2[k][0], B0.s, acc, 0, 0, 0);
            acc = __builtin_amdgcn_mfma_f32_16x16x32_bf16(a2[k][1], B1.s, acc, 0, 0, 0);
            acc = __builtin_amdgcn_mfma_f32_16x16x32_bf16(a2[k][2], B2.s, acc, 0, 0, 0);
            acc = __builtin_amdgcn_mfma_f32_16x16x32_bf16(a2[k][3], B3.s, acc, 0, 0, 0);
            const int rb = k * 32 + w * 16 + 4 * hi;
            #pragma unroll
            for (int j = 0; j < 4; ++j) {
                const float y = fmaxf(fmaf(sc, acc[j], tb), 0.f);
                X0V(rb + j, ct * 16 + lo) = f2bf(y);
            }
        }
    }

    // ---- convert chunk B -> pk[6..11] ----
    #pragma unroll
    for (int it = 0; it < 2; ++it) {
        const float4 f0 = frB[it * 4 + 0], f1 = frB[it * 4 + 1];
        const float4 f2 = frB[it * 4 + 2], f3 = frB[it * 4 + 3];
        pk[6 + it * 3 + 0].x = f2bf(f0.x) | (f2bf(f1.x) << 16);
        pk[6 + it * 3 + 0].y = f2bf(f2.x) | (f2bf(f3.x) << 16);
        pk[6 + it * 3 + 1].x = f2bf(f0.y) | (f2bf(f1.y) << 16);
        pk[6 + it * 3 + 1].y = f2bf(f2.y) | (f2bf(f3.y) << 16);
        pk[6 + it * 3 + 2].x = f2bf(f0.z) | (f2bf(f1.z) << 16);
        pk[6 + it * 3 + 2].y = f2bf(f2.z) | (f2bf(f3.z) << 16);
    }

    // ---- a3 fragments tile0 (wave-private X2 rows) ----
    short8v a3[3][2];
    #pragma unroll
    for (int k = 0; k < 3; ++k) {
        const int row = k * 32 + w * 16 + lo;
        a3[k][0] = *(const short8v*)&X0V(row, hi * 8);
        a3[k][1] = *(const short8v*)&X0V(row, 32 + hi * 8);
    }
    __syncthreads();   // B4: all waves' X2/a3 reads done -> X0 region reusable

    // ---- tile1 staging write (from pk regs) ----
    #pragma unroll
    for (int it = 0; it < 4; ++it) {
        const int c0 = it * 16 + cg * 4;
        *(uint2*)&X0V(0 * 32 + p, c0) = pk[it * 3 + 0];
        *(uint2*)&X0V(1 * 32 + p, c0) = pk[it * 3 + 1];
        *(uint2*)&X0V(2 * 32 + p, c0) = pk[it * 3 + 2];
    }
    if (rel) {
        const float d0 = prs0 - prt0, d1 = prs1 - prt1, d2 = prs2 - prt2;
        const float ds = d0 * d0 + d1 * d1 + d2 * d2;
        uint2 wr; wr.x = f2bf(d0) | (f2bf(d1) << 16); wr.y = f2bf(d2) | (f2bf(ds) << 16);
        *(uint2*)&X0V(rk * 32 + rp, 64) = wr;
    }

    // ---- layer 3 tile0 + store ----
    #pragma unroll 2
    for (int ct = 0; ct < 4; ++ct) {
        FragU B0, B1;
        B0.u = w3f[(ct * 2 + 0) * 64 + lane];
        B1.u = w3f[(ct * 2 + 1) * 64 + lane];
        const float sc = s3w[ct * 16 + lo];
        const float tb = t3w[ct * 16 + lo];
        f32x4 acc0 = {0.f, 0.f, 0.f, 0.f};
        f32x4 acc1 = {0.f, 0.f, 0.f, 0.f};
        f32x4 acc2 = {0.f, 0.f, 0.f, 0.f};
        acc0 = __builtin_amdgcn_mfma_f32_16x16x32_bf16(a3[0][0], B0.s, acc0, 0, 0, 0);
        acc0 = __builtin_amdgcn_mfma_f32_16x16x32_bf16(a3[0][1], B1.s, acc0, 0, 0, 0);
        acc1 = __builtin_amdgcn_mfma_f32_16x16x32_bf16(a3[1][0], B0.s, acc1, 0, 0, 0);
        acc1 = __builtin_amdgcn_mfma_f32_16x16x32_bf16(a3[1][1], B1.s, acc1, 0, 0, 0);
        acc2 = __builtin_amdgcn_mfma_f32_16x16x32_bf16(a3[2][0], B0.s, acc2, 0, 0, 0);
        acc2 = __builtin_amdgcn_mfma_f32_16x16x32_bf16(a3[2][1], B1.s, acc2, 0, 0, 0);
        float4 r;
        float* rp4 = &r.x;
        #pragma unroll
        for (int j = 0; j < 4; ++j) {
            rp4[j] = fmaxf(fmaf(sc, acc0[j], tb), 0.f)
                   + fmaxf(fmaf(sc, acc1[j], tb), 0.f)
                   + fmaxf(fmaf(sc, acc2[j], tb), 0.f);
        }
        float* op = out + (size_t)(b0 * 64 + ct * 16 + lo) * N + n00 + w * 16 + 4 * hi;
        *(float4*)op = r;
    }
    __syncthreads();   // B5: tile1 X0 staged (all staging writes visible)

    // ================= tile1 compute (plain R4 path) =================
    #pragma unroll
    for (int k = 0; k < 3; ++k) {
        const int row = k * 32 + w * 16 + lo;
        a1[k][0] = *(const short8v*)&X0V(row, hi * 8);
        a1[k][1] = *(const short8v*)&X0V(row, 32 + hi * 8);
        FragU U; U.u.x = 0; U.u.y = 0; U.u.z = 0; U.u.w = 0;
        if (hi == 0) U.h[0] = *(const uint2*)&X0V(row, 64);
        a1[k][2] = U.s;
    }
    __syncthreads();   // B6: X0 dead

    #pragma unroll 2
    for (int ct = 0; ct < 8; ++ct) {
        FragU B0, B1, B2;
        B0.u = w1f[(ct * 3 + 0) * 64 + lane];
        B1.u = w1f[(ct * 3 + 1) * 64 + lane];
        B2.u = w1f[(ct * 3 + 2) * 64 + lane];
        const float sc = s1w[ct * 16 + lo];
        const float tb = t1w[ct * 16 + lo];
        #pragma unroll
        for (int k = 0; k < 3; ++k) {
            f32x4 acc = {0.f, 0.f, 0.f, 0.f};
            acc = __builtin_amdgcn_mfma_f32_16x16x32_bf16(a1[k][0], B0.s, acc, 0, 0, 0);
            acc = __builtin_amdgcn_mfma_f32_16x16x32_bf16(a1[k][1], B1.s, acc, 0, 0, 0);
            acc = __builtin_amdgcn_mfma_f32_16x16x32_bf16(a1[k][2], B2.s, acc, 0, 0, 0);
            const int rb = k * 32 + w * 16 + 4 * hi;
            #pragma unroll
            for (int j = 0; j < 4; ++j) {
                const float y = fmaxf(fmaf(sc, acc[j], tb), 0.f);
                X1V(rb + j, ct * 16 + lo) = f2bf(y);
            }
        }
    }

    #pragma unroll
    for (int k = 0; k < 3; ++k) {
        const int row = k * 32 + w * 16 + lo;
        #pragma unroll
        for (int ks = 0; ks < 4; ++ks)
            a2[k][ks] = *(const short8v*)&X1V(row, ks * 32 + hi * 8);
    }
    __syncthreads();   // B7: X1 dead

    #pragma unroll 2
    for (int ct = 0; ct < 4; ++ct) {
        FragU B0, B1, B2, B3;
        B0.u = w2f[(ct * 4 + 0) * 64 + lane];
        B1.u = w2f[(ct * 4 + 1) * 64 + lane];
        B2.u = w2f[(ct * 4 + 2) * 64 + lane];
        B3.u = w2f[(ct * 4 + 3) * 64 + lane];
        const float sc = s2w[ct * 16 + lo];
        const float tb = t2w[ct * 16 + lo];
        #pragma unroll
        for (int k = 0; k < 3; ++k) {
            f32x4 acc = {0.f, 0.f, 0.f, 0.f};
            acc = __builtin_amdgcn_mfma_f32_16x16x32_bf16(a2[k][0], B0.s, acc, 0, 0, 0);
            acc = __builtin_amdgcn_mfma_f32_16x16x32_bf16(a2[k][1], B1.s, acc, 0, 0, 0);
            acc = __builtin_amdgcn_mfma_f32_16x16x32_bf16(a2[k][2], B2.s, acc, 0, 0, 0);
            acc = __builtin_amdgcn_mfma_f32_16x16x32_bf16(a2[k][3], B3.s, acc, 0, 0, 0);
            const int rb = k * 32 + w * 16 + 4 * hi;
            #pragma unroll
            for (int j = 0; j < 4; ++j) {
                const float y = fmaxf(fmaf(sc, acc[j], tb), 0.f);
                X0V(rb + j, ct * 16 + lo) = f2bf(y);
            }
        }
    }

    #pragma unroll
    for (int k = 0; k < 3; ++k) {
        const int row = k * 32 + w * 16 + lo;
        a3[k][0] = *(const short8v*)&X0V(row, hi * 8);
        a3[k][1] = *(const short8v*)&X0V(row, 32 + hi * 8);
    }
    #pragma unroll 2
    for (int ct = 0; ct < 4; ++ct) {
        FragU B0, B1;
        B0.u = w3f[(ct * 2 + 0) * 64 + lane];
        B1.u = w3f[(ct * 2 + 1) * 64 + lane];
        const float sc = s3w[ct * 16 + lo];
        const float tb = t3w[ct * 16 + lo];
        f32x4 acc0 = {0.f, 0.f, 0.f, 0.f};
        f32x4 acc1 = {0.f, 0.f, 0.f, 0.f};
        f32x4 acc2 = {0.f, 0.f, 0.f, 0.f};
        acc0 = __builtin_amdgcn_mfma_f32_16x16x32_bf16(a3[0][0], B0.s, acc0, 0, 0, 0);
        acc0 = __builtin_amdgcn_mfma_f32_16x16x32_bf16(a3[0][1], B1.s, acc0, 0, 0, 0);
        acc1 = __builtin_amdgcn_mfma_f32_16x16x32_bf16(a3[1][0], B0.s, acc1, 0, 0, 0);
        acc1 = __builtin_amdgcn_mfma_f32_16x16x32_bf16(a3[1][1], B1.s, acc1, 0, 0, 0);
        acc2 = __builtin_amdgcn_mfma_f32_16x16x32_bf16(a3[2][0], B0.s, acc2, 0, 0, 0);
        acc2 = __builtin_amdgcn_mfma_f32_16x16x32_bf16(a3[2][1], B1.s, acc2, 0, 0, 0);
        float4 r;
        float* rp4 = &r.x;
        #pragma unroll
        for (int j = 0; j < 4; ++j) {
            rp4[j] = fmaxf(fmaf(sc, acc0[j], tb), 0.f)
                   + fmaxf(fmaf(sc, acc1[j], tb), 0.f)
                   + fmaxf(fmaf(sc, acc2[j], tb), 0.f);
        }
        float* op = out + (size_t)(b1t * 64 + ct * 16 + lo) * N + n01 + w * 16 + 4 * hi;
        *(float4*)op = r;
    }
    #undef X0V
    #undef X1V
}

extern "C" void kernel_launch(void* const* d_in, const int* in_sizes, int n_in,
                              void* d_out, int out_size, void* d_ws, size_t ws_size,
                              hipStream_t stream)
{
    const float* src  = (const float*)d_in[0];
    const float* tgt  = (const float*)d_in[1];
    const float* feat = (const float*)d_in[2];
    const float* W1 = (const float*)d_in[3];
    const float* g1 = (const float*)d_in[4];
    const float* b1 = (const float*)d_in[5];
    const float* m1 = (const float*)d_in[6];
    const float* v1 = (const float*)d_in[7];
    const float* W2 = (const float*)d_in[8];
    const float* g2 = (const float*)d_in[9];
    const float* b2 = (const float*)d_in[10];
    const float* m2 = (const float*)d_in[11];
    const float* v2 = (const float*)d_in[12];
    const float* W3 = (const float*)d_in[13];
    const float* g3 = (const float*)d_in[14];
    const float* b3 = (const float*)d_in[15];
    const float* m3 = (const float*)d_in[16];
    const float* v3 = (const float*)d_in[17];
    float* out = (float*)d_out;
    char* ws = (char*)d_ws;

    hipLaunchKernelGGL(fa_pack, dim3(13), dim3(256), 0, stream,
                       W1, g1, b1, m1, v1, W2, g2, b2, m2, v2, W3, g3, b3, m3, v3, ws);
    hipLaunchKernelGGL(fa_mfma, dim3(2048), dim3(128), 0, stream,
                       src, tgt, feat, ws, out);
}

// Round 6
// 141.104 us; speedup vs baseline: 1.0932x; 1.0932x over previous
//
#include <hip/hip_runtime.h>

// FeatureAggregation via MFMA bf16 (fp32 accumulate).
// 1-wave workgroups (64 threads, 16 points), ZERO cross-wave barriers:
// all LDS ordering is intra-wave s_waitcnt lgkmcnt(0) (no vmcnt drains),
// so waves run fully independently and self-hide HBM latency (14 blocks/CU).
// Verified R2/R4 fragment layouts and epilogues kept identical.
// B=8, C=64, N=16384, K=16 but only k<3 used (reference quirk).

typedef __attribute__((ext_vector_type(8))) short short8v;
typedef __attribute__((ext_vector_type(4))) float f32x4;

#define BN_EPS 1e-5f

// intra-wave LDS fence: order prior ds_write/ds_read against later ones
// (rule #18: sched_barrier needed around inline-asm waitcnt)
#define LDS_FENCE() do {                                        \
    __builtin_amdgcn_sched_barrier(0);                          \
    asm volatile("s_waitcnt lgkmcnt(0)" ::: "memory");          \
    __builtin_amdgcn_sched_barrier(0);                          \
} while (0)

__device__ __forceinline__ unsigned short f2bf(float f) {
    union { float f; unsigned u; } U; U.f = f;
    unsigned r = U.u + 0x7FFFu + ((U.u >> 16) & 1u);   // RNE; inputs finite
    return (unsigned short)(r >> 16);
}

union FragU { uint4 u; short8v s; uint2 h[2]; };

// ---- d_ws layout (bytes) ----
//     0 : W1 frags uint4[1536]  (frag = ct*3+ks, ct 0..7, ks 0..2; zero-pad k>=68)
// 24576 : W2 frags uint4[1024]  (frag = ct*4+ks, ct 0..3, ks 0..3)
// 40960 : W3 frags uint4[512]   (frag = ct*2+ks, ct 0..3, ks 0..1)
// 49152 : s1[128]  49664 : t1[128]
// 50176 : s2[64]   50432 : t2[64]
// 50688 : s3[64]   50944 : t3[64]

__global__ __launch_bounds__(256) void fa_pack(
    const float* __restrict__ W1, const float* __restrict__ g1, const float* __restrict__ b1,
    const float* __restrict__ m1, const float* __restrict__ v1,
    const float* __restrict__ W2, const float* __restrict__ g2, const float* __restrict__ b2,
    const float* __restrict__ m2, const float* __restrict__ v2,
    const float* __restrict__ W3, const float* __restrict__ g3, const float* __restrict__ b3,
    const float* __restrict__ m3, const float* __restrict__ v3,
    char* __restrict__ ws)
{
    const int id = blockIdx.x * 256 + threadIdx.x;
    if (id < 1536) {                       // W1: 96(K,zero-padded) x 128
        const int lane = id & 63, frag = id >> 6;
        const int ct = frag / 3, ks = frag - 3 * ct;
        const int o  = ct * 16 + (lane & 15);
        const int kb = ks * 32 + (lane >> 4) * 8;
        unsigned short h[8];
        #pragma unroll
        for (int j = 0; j < 8; ++j) {
            const int k = kb + j;
            h[j] = (k < 68) ? f2bf(W1[o * 68 + k]) : (unsigned short)0;
        }
        uint4 pk;
        pk.x = h[0] | (h[1] << 16); pk.y = h[2] | (h[3] << 16);
        pk.z = h[4] | (h[5] << 16); pk.w = h[6] | (h[7] << 16);
        ((uint4*)ws)[id] = pk;
    } else if (id < 2560) {                // W2: 128 x 64
        const int i2 = id - 1536;
        const int lane = i2 & 63, frag = i2 >> 6;
        const int o  = (frag >> 2) * 16 + (lane & 15);
        const int kb = (frag & 3) * 32 + (lane >> 4) * 8;
        unsigned short h[8];
        #pragma unroll
        for (int j = 0; j < 8; ++j) h[j] = f2bf(W2[o * 128 + kb + j]);
        uint4 pk;
        pk.x = h[0] | (h[1] << 16); pk.y = h[2] | (h[3] << 16);
        pk.z = h[4] | (h[5] << 16); pk.w = h[6] | (h[7] << 16);
        ((uint4*)(ws + 24576))[i2] = pk;
    } else if (id < 3072) {                // W3: 64 x 64
        const int i3 = id - 2560;
        const int lane = i3 & 63, frag = i3 >> 6;
        const int o  = (frag >> 1) * 16 + (lane & 15);
        const int kb = (frag & 1) * 32 + (lane >> 4) * 8;
        unsigned short h[8];
        #pragma unroll
        for (int j = 0; j < 8; ++j) h[j] = f2bf(W3[o * 64 + kb + j]);
        uint4 pk;
        pk.x = h[0] | (h[1] << 16); pk.y = h[2] | (h[3] << 16);
        pk.z = h[4] | (h[5] << 16); pk.w = h[6] | (h[7] << 16);
        ((uint4*)(ws + 40960))[i3] = pk;
    } else if (id < 3200) {                // BN fold L1
        const int o = id - 3072;
        const float s = g1[o] * rsqrtf(v1[o] + BN_EPS);
        ((float*)(ws + 49152))[o] = s;
        ((float*)(ws + 49664))[o] = b1[o] - m1[o] * s;
    } else if (id < 3264) {                // BN fold L2
        const int o = id - 3200;
        const float s = g2[o] * rsqrtf(v2[o] + BN_EPS);
        ((float*)(ws + 50176))[o] = s;
        ((float*)(ws + 50432))[o] = b2[o] - m2[o] * s;
    } else if (id < 3328) {                // BN fold L3
        const int o = id - 3264;
        const float s = g3[o] * rsqrtf(v3[o] + BN_EPS);
        ((float*)(ws + 50688))[o] = s;
        ((float*)(ws + 50944))[o] = b3[o] - m3[o] * s;
    }
}

__global__ __launch_bounds__(64, 3) void fa_mfma(
    const float* __restrict__ src, const float* __restrict__ tgt,
    const float* __restrict__ feat,
    const char* __restrict__ ws, float* __restrict__ out)
{
    constexpr int N = 16384;
    // X0: 48 rows (k*16+p) x stride 72 (input; cols 0..63 reused as X2 output)
    // Y : 16 rows (points) x stride 136 (per-k layer-1 output scratch)
    __shared__ unsigned short X0[48 * 72];   // 6912 B
    __shared__ unsigned short Y[16 * 136];   // 4352 B -> 11264 B total, 14 blk/CU

    const int t  = threadIdx.x;                 // one wave per block
    const int b  = blockIdx.x >> 10;            // 8 batches x 1024 tiles
    const int n0 = (blockIdx.x & 1023) << 4;    // 16 points per tile

    const int p  = t & 15;
    const int cs = t >> 4;                      // 0..3

    // ---- stage X0: issue ALL global loads before any conversion ----
    {
        float4 fr[16];
        #pragma unroll
        for (int it = 0; it < 4; ++it) {
            const float* fp = feat + ((size_t)(b * 64 + it * 16 + cs * 4) * N + n0 + p) * 16;
            #pragma unroll
            for (int q = 0; q < 4; ++q)
                fr[it * 4 + q] = *(const float4*)(fp + (size_t)q * N * 16);
        }
        float rs0 = 0, rs1 = 0, rs2 = 0, rt0 = 0, rt1 = 0, rt2 = 0;
        const bool rel = t < 48;
        const int rp = t & 15, rk = t >> 4;
        if (rel) {
            const int n = n0 + rp;
            rs0 = src[((b * 3 + 0) * N + n) * 16 + rk]; rt0 = tgt[(b * 3 + 0) * N + n];
            rs1 = src[((b * 3 + 1) * N + n) * 16 + rk]; rt1 = tgt[(b * 3 + 1) * N + n];
            rs2 = src[((b * 3 + 2) * N + n) * 16 + rk]; rt2 = tgt[(b * 3 + 2) * N + n];
        }
        #pragma unroll
        for (int it = 0; it < 4; ++it) {
            const int c0 = it * 16 + cs * 4;
            const float4 f0 = fr[it * 4 + 0], f1 = fr[it * 4 + 1];
            const float4 f2 = fr[it * 4 + 2], f3 = fr[it * 4 + 3];
            uint2 u0, u1, u2;
            u0.x = f2bf(f0.x) | (f2bf(f1.x) << 16); u0.y = f2bf(f2.x) | (f2bf(f3.x) << 16);
            u1.x = f2bf(f0.y) | (f2bf(f1.y) << 16); u1.y = f2bf(f2.y) | (f2bf(f3.y) << 16);
            u2.x = f2bf(f0.z) | (f2bf(f1.z) << 16); u2.y = f2bf(f2.z) | (f2bf(f3.z) << 16);
            *(uint2*)&X0[(0 * 16 + p) * 72 + c0] = u0;
            *(uint2*)&X0[(1 * 16 + p) * 72 + c0] = u1;
            *(uint2*)&X0[(2 * 16 + p) * 72 + c0] = u2;
        }
        if (rel) {
            const float d0 = rs0 - rt0, d1 = rs1 - rt1, d2 = rs2 - rt2;
            const float ds = d0 * d0 + d1 * d1 + d2 * d2;
            uint2 wr; wr.x = f2bf(d0) | (f2bf(d1) << 16); wr.y = f2bf(d2) | (f2bf(ds) << 16);
            *(uint2*)&X0[(rk * 16 + rp) * 72 + 64] = wr;
        }
    }
    LDS_FENCE();   // X0 writes -> a1 reads (same wave)

    const int lo = t & 15, hi = t >> 4;

    const uint4*  w1f = (const uint4*)ws;
    const uint4*  w2f = (const uint4*)(ws + 24576);
    const uint4*  w3f = (const uint4*)(ws + 40960);
    const float*  s1w = (const float*)(ws + 49152);
    const float*  t1w = (const float*)(ws + 49664);
    const float*  s2w = (const float*)(ws + 50176);
    const float*  t2w = (const float*)(ws + 50432);
    const float*  s3w = (const float*)(ws + 50688);
    const float*  t3w = (const float*)(ws + 50944);

    // ---- per-k: layer 1 (K=96, 68 real -> 128) into Y, consume into a2 ----
    short8v a2[3][4];
    #pragma unroll
    for (int k = 0; k < 3; ++k) {
        const int row = k * 16 + lo;
        const short8v a10 = *(const short8v*)&X0[row * 72 + hi * 8];
        const short8v a11 = *(const short8v*)&X0[row * 72 + 32 + hi * 8];
        short8v a12;
        {
            FragU U; U.u.x = 0; U.u.y = 0; U.u.z = 0; U.u.w = 0;
            if (hi == 0) U.h[0] = *(const uint2*)&X0[row * 72 + 64];
            a12 = U.s;
        }
        #pragma unroll 2
        for (int ct = 0; ct < 8; ++ct) {
            FragU B0, B1, B2;
            B0.u = w1f[(ct * 3 + 0) * 64 + t];
            B1.u = w1f[(ct * 3 + 1) * 64 + t];
            B2.u = w1f[(ct * 3 + 2) * 64 + t];
            const float sc = s1w[ct * 16 + lo];
            const float tb = t1w[ct * 16 + lo];
            f32x4 acc = {0.f, 0.f, 0.f, 0.f};
            acc = __builtin_amdgcn_mfma_f32_16x16x32_bf16(a10, B0.s, acc, 0, 0, 0);
            acc = __builtin_amdgcn_mfma_f32_16x16x32_bf16(a11, B1.s, acc, 0, 0, 0);
            acc = __builtin_amdgcn_mfma_f32_16x16x32_bf16(a12, B2.s, acc, 0, 0, 0);
            #pragma unroll
            for (int j = 0; j < 4; ++j) {
                const float y = fmaxf(fmaf(sc, acc[j], tb), 0.f);
                Y[(4 * hi + j) * 136 + ct * 16 + lo] = f2bf(y);
            }
        }
        LDS_FENCE();   // Y writes -> a2 reads
        #pragma unroll
        for (int ks = 0; ks < 4; ++ks)
            a2[k][ks] = *(const short8v*)&Y[lo * 136 + ks * 32 + hi * 8];
        LDS_FENCE();   // a2 reads -> next k's Y writes (WAR)
    }

    // ---- layer 2 : K=128 -> 64, write X2 (X0 region, cols 0..63) ----
    #pragma unroll 2
    for (int ct = 0; ct < 4; ++ct) {
        FragU B0, B1, B2, B3;
        B0.u = w2f[(ct * 4 + 0) * 64 + t];
        B1.u = w2f[(ct * 4 + 1) * 64 + t];
        B2.u = w2f[(ct * 4 + 2) * 64 + t];
        B3.u = w2f[(ct * 4 + 3) * 64 + t];
        const float sc = s2w[ct * 16 + lo];
        const float tb = t2w[ct * 16 + lo];
        #pragma unroll
        for (int k = 0; k < 3; ++k) {
            f32x4 acc = {0.f, 0.f, 0.f, 0.f};
            acc = __builtin_amdgcn_mfma_f32_16x16x32_bf16(a2[k][0], B0.s, acc, 0, 0, 0);
            acc = __builtin_amdgcn_mfma_f32_16x16x32_bf16(a2[k][1], B1.s, acc, 0, 0, 0);
            acc = __builtin_amdgcn_mfma_f32_16x16x32_bf16(a2[k][2], B2.s, acc, 0, 0, 0);
            acc = __builtin_amdgcn_mfma_f32_16x16x32_bf16(a2[k][3], B3.s, acc, 0, 0, 0);
            const int rb = k * 16 + 4 * hi;
            #pragma unroll
            for (int j = 0; j < 4; ++j) {
                const float y = fmaxf(fmaf(sc, acc[j], tb), 0.f);
                X0[(rb + j) * 72 + ct * 16 + lo] = f2bf(y);
            }
        }
    }
    LDS_FENCE();   // X2 writes -> a3 reads

    // ---- layer 3 : K=64 -> 64, BN+ReLU per k then register k-sum ----
    short8v a3[3][2];
    #pragma unroll
    for (int k = 0; k < 3; ++k) {
        const int row = k * 16 + lo;
        a3[k][0] = *(const short8v*)&X0[row * 72 + hi * 8];
        a3[k][1] = *(const short8v*)&X0[row * 72 + 32 + hi * 8];
    }
    #pragma unroll 2
    for (int ct = 0; ct < 4; ++ct) {
        FragU B0, B1;
        B0.u = w3f[(ct * 2 + 0) * 64 + t];
        B1.u = w3f[(ct * 2 + 1) * 64 + t];
        const float sc = s3w[ct * 16 + lo];
        const float tb = t3w[ct * 16 + lo];
        f32x4 acc0 = {0.f, 0.f, 0.f, 0.f};
        f32x4 acc1 = {0.f, 0.f, 0.f, 0.f};
        f32x4 acc2 = {0.f, 0.f, 0.f, 0.f};
        acc0 = __builtin_amdgcn_mfma_f32_16x16x32_bf16(a3[0][0], B0.s, acc0, 0, 0, 0);
        acc0 = __builtin_amdgcn_mfma_f32_16x16x32_bf16(a3[0][1], B1.s, acc0, 0, 0, 0);
        acc1 = __builtin_amdgcn_mfma_f32_16x16x32_bf16(a3[1][0], B0.s, acc1, 0, 0, 0);
        acc1 = __builtin_amdgcn_mfma_f32_16x16x32_bf16(a3[1][1], B1.s, acc1, 0, 0, 0);
        acc2 = __builtin_amdgcn_mfma_f32_16x16x32_bf16(a3[2][0], B0.s, acc2, 0, 0, 0);
        acc2 = __builtin_amdgcn_mfma_f32_16x16x32_bf16(a3[2][1], B1.s, acc2, 0, 0, 0);
        float4 r;
        float* rp4 = &r.x;
        #pragma unroll
        for (int j = 0; j < 4; ++j) {
            rp4[j] = fmaxf(fmaf(sc, acc0[j], tb), 0.f)
                   + fmaxf(fmaf(sc, acc1[j], tb), 0.f)
                   + fmaxf(fmaf(sc, acc2[j], tb), 0.f);
        }
        float* op = out + (size_t)(b * 64 + ct * 16 + lo) * N + n0 + 4 * hi;
        *(float4*)op = r;   // 4 lanes per o cover a full 64B line
    }
}

extern "C" void kernel_launch(void* const* d_in, const int* in_sizes, int n_in,
                              void* d_out, int out_size, void* d_ws, size_t ws_size,
                              hipStream_t stream)
{
    const float* src  = (const float*)d_in[0];
    const float* tgt  = (const float*)d_in[1];
    const float* feat = (const float*)d_in[2];
    const float* W1 = (const float*)d_in[3];
    const float* g1 = (const float*)d_in[4];
    const float* b1 = (const float*)d_in[5];
    const float* m1 = (const float*)d_in[6];
    const float* v1 = (const float*)d_in[7];
    const float* W2 = (const float*)d_in[8];
    const float* g2 = (const float*)d_in[9];
    const float* b2 = (const float*)d_in[10];
    const float* m2 = (const float*)d_in[11];
    const float* v2 = (const float*)d_in[12];
    const float* W3 = (const float*)d_in[13];
    const float* g3 = (const float*)d_in[14];
    const float* b3 = (const float*)d_in[15];
    const float* m3 = (const float*)d_in[16];
    const float* v3 = (const float*)d_in[17];
    float* out = (float*)d_out;
    char* ws = (char*)d_ws;

    hipLaunchKernelGGL(fa_pack, dim3(13), dim3(256), 0, stream,
                       W1, g1, b1, m1, v1, W2, g2, b2, m2, v2, W3, g3, b3, m3, v3, ws);
    hipLaunchKernelGGL(fa_mfma, dim3(8 * 1024), dim3(64), 0, stream,
                       src, tgt, feat, ws, out);
}

// Round 7
// 135.796 us; speedup vs baseline: 1.1360x; 1.0391x over previous
//
#include <hip/hip_runtime.h>

// FeatureAggregation via MFMA bf16 (fp32 accumulate).
// R4 verified compute core, widened to 64-point tiles with CONTIGUOUS staging:
// each wave-instruction reads 64 consecutive points of one channel (4KB window)
// instead of 16 points x 4 channel-groups (4 regions 4MB apart) -> better
// DRAM row / TLB locality. B=8, C=64, N=16384, K=16, only k<3 used (quirk).

typedef __attribute__((ext_vector_type(8))) short short8v;
typedef __attribute__((ext_vector_type(4))) float f32x4;

#define BN_EPS 1e-5f

__device__ __forceinline__ unsigned short f2bf(float f) {
    union { float f; unsigned u; } U; U.f = f;
    unsigned r = U.u + 0x7FFFu + ((U.u >> 16) & 1u);   // RNE; inputs finite
    return (unsigned short)(r >> 16);
}

union FragU { uint4 u; short8v s; uint2 h[2]; };

// ---- d_ws layout (bytes) ----
//     0 : W1 frags uint4[1536]  (frag = ct*3+ks, ct 0..7, ks 0..2; zero-pad k>=68)
// 24576 : W2 frags uint4[1024]  (frag = ct*4+ks, ct 0..3, ks 0..3)
// 40960 : W3 frags uint4[512]   (frag = ct*2+ks, ct 0..3, ks 0..1)
// 49152 : s1[128]  49664 : t1[128]
// 50176 : s2[64]   50432 : t2[64]
// 50688 : s3[64]   50944 : t3[64]

__global__ __launch_bounds__(256) void fa_pack(
    const float* __restrict__ W1, const float* __restrict__ g1, const float* __restrict__ b1,
    const float* __restrict__ m1, const float* __restrict__ v1,
    const float* __restrict__ W2, const float* __restrict__ g2, const float* __restrict__ b2,
    const float* __restrict__ m2, const float* __restrict__ v2,
    const float* __restrict__ W3, const float* __restrict__ g3, const float* __restrict__ b3,
    const float* __restrict__ m3, const float* __restrict__ v3,
    char* __restrict__ ws)
{
    const int id = blockIdx.x * 256 + threadIdx.x;
    if (id < 1536) {                       // W1: 96(K,zero-padded) x 128
        const int lane = id & 63, frag = id >> 6;
        const int ct = frag / 3, ks = frag - 3 * ct;
        const int o  = ct * 16 + (lane & 15);
        const int kb = ks * 32 + (lane >> 4) * 8;
        unsigned short h[8];
        #pragma unroll
        for (int j = 0; j < 8; ++j) {
            const int k = kb + j;
            h[j] = (k < 68) ? f2bf(W1[o * 68 + k]) : (unsigned short)0;
        }
        uint4 pk;
        pk.x = h[0] | (h[1] << 16); pk.y = h[2] | (h[3] << 16);
        pk.z = h[4] | (h[5] << 16); pk.w = h[6] | (h[7] << 16);
        ((uint4*)ws)[id] = pk;
    } else if (id < 2560) {                // W2: 128 x 64
        const int i2 = id - 1536;
        const int lane = i2 & 63, frag = i2 >> 6;
        const int o  = (frag >> 2) * 16 + (lane & 15);
        const int kb = (frag & 3) * 32 + (lane >> 4) * 8;
        unsigned short h[8];
        #pragma unroll
        for (int j = 0; j < 8; ++j) h[j] = f2bf(W2[o * 128 + kb + j]);
        uint4 pk;
        pk.x = h[0] | (h[1] << 16); pk.y = h[2] | (h[3] << 16);
        pk.z = h[4] | (h[5] << 16); pk.w = h[6] | (h[7] << 16);
        ((uint4*)(ws + 24576))[i2] = pk;
    } else if (id < 3072) {                // W3: 64 x 64
        const int i3 = id - 2560;
        const int lane = i3 & 63, frag = i3 >> 6;
        const int o  = (frag >> 1) * 16 + (lane & 15);
        const int kb = (frag & 1) * 32 + (lane >> 4) * 8;
        unsigned short h[8];
        #pragma unroll
        for (int j = 0; j < 8; ++j) h[j] = f2bf(W3[o * 64 + kb + j]);
        uint4 pk;
        pk.x = h[0] | (h[1] << 16); pk.y = h[2] | (h[3] << 16);
        pk.z = h[4] | (h[5] << 16); pk.w = h[6] | (h[7] << 16);
        ((uint4*)(ws + 40960))[i3] = pk;
    } else if (id < 3200) {                // BN fold L1
        const int o = id - 3072;
        const float s = g1[o] * rsqrtf(v1[o] + BN_EPS);
        ((float*)(ws + 49152))[o] = s;
        ((float*)(ws + 49664))[o] = b1[o] - m1[o] * s;
    } else if (id < 3264) {                // BN fold L2
        const int o = id - 3200;
        const float s = g2[o] * rsqrtf(v2[o] + BN_EPS);
        ((float*)(ws + 50176))[o] = s;
        ((float*)(ws + 50432))[o] = b2[o] - m2[o] * s;
    } else if (id < 3328) {                // BN fold L3
        const int o = id - 3264;
        const float s = g3[o] * rsqrtf(v3[o] + BN_EPS);
        ((float*)(ws + 50688))[o] = s;
        ((float*)(ws + 50944))[o] = b3[o] - m3[o] * s;
    }
}

__global__ __launch_bounds__(256, 3) void fa_mfma(
    const float* __restrict__ src, const float* __restrict__ tgt,
    const float* __restrict__ feat,
    const char* __restrict__ ws, float* __restrict__ out)
{
    constexpr int N = 16384;
    // ONE shared buffer, overlaid views (phases separated by barriers):
    //   X0 view: 192 rows (k*64+p) x stride 72 (input; later layer-2 output X2)
    //   X1 view: 192 rows x stride 136 (layer-1 output)
    __shared__ unsigned short SM[192 * 136];   // 52224 B -> 3 blocks/CU
    #define X0V(r, c) SM[(r) * 72 + (c)]
    #define X1V(r, c) SM[(r) * 136 + (c)]

    const int t  = threadIdx.x;
    const int b  = blockIdx.x >> 8;             // 8 batches x 256 tiles
    const int n0 = (blockIdx.x & 255) << 6;     // 64 points per tile

    // ---- stage X0: contiguous wave reads (64 consecutive points, 1 channel) ----
    {
        const int p  = t & 63;
        const int cg = t >> 6;                  // 0..3 (16 channels each)
        float4 fr[16];
        #pragma unroll
        for (int i = 0; i < 16; ++i) {
            const int c = cg * 16 + i;
            fr[i] = *(const float4*)(feat + ((size_t)(b * 64 + c) * N + n0 + p) * 16);
        }
        float rs0 = 0, rs1 = 0, rs2 = 0, rt0 = 0, rt1 = 0, rt2 = 0;
        const bool rel = t < 192;
        const int rp = t & 63, rk = t >> 6;     // rk 0..2 when rel
        if (rel) {
            const int n = n0 + rp;
            rs0 = src[((b * 3 + 0) * N + n) * 16 + rk]; rt0 = tgt[(b * 3 + 0) * N + n];
            rs1 = src[((b * 3 + 1) * N + n) * 16 + rk]; rt1 = tgt[(b * 3 + 1) * N + n];
            rs2 = src[((b * 3 + 2) * N + n) * 16 + rk]; rt2 = tgt[(b * 3 + 2) * N + n];
        }
        #pragma unroll
        for (int j = 0; j < 4; ++j) {
            const int c0 = cg * 16 + 4 * j;
            const float4 f0 = fr[4 * j + 0], f1 = fr[4 * j + 1];
            const float4 f2 = fr[4 * j + 2], f3 = fr[4 * j + 3];
            uint2 u0, u1, u2;
            u0.x = f2bf(f0.x) | (f2bf(f1.x) << 16); u0.y = f2bf(f2.x) | (f2bf(f3.x) << 16);
            u1.x = f2bf(f0.y) | (f2bf(f1.y) << 16); u1.y = f2bf(f2.y) | (f2bf(f3.y) << 16);
            u2.x = f2bf(f0.z) | (f2bf(f1.z) << 16); u2.y = f2bf(f2.z) | (f2bf(f3.z) << 16);
            *(uint2*)&X0V(0 * 64 + p, c0) = u0;
            *(uint2*)&X0V(1 * 64 + p, c0) = u1;
            *(uint2*)&X0V(2 * 64 + p, c0) = u2;
        }
        if (rel) {
            const float d0 = rs0 - rt0, d1 = rs1 - rt1, d2 = rs2 - rt2;
            const float ds = d0 * d0 + d1 * d1 + d2 * d2;
            uint2 wr; wr.x = f2bf(d0) | (f2bf(d1) << 16); wr.y = f2bf(d2) | (f2bf(ds) << 16);
            *(uint2*)&X0V(rk * 64 + rp, 64) = wr;
        }
    }
    __syncthreads();   // B1: X0 staged

    const int w = t >> 6, lane = t & 63, lo = lane & 15, hi = lane >> 4;

    const uint4*  w1f = (const uint4*)ws;
    const uint4*  w2f = (const uint4*)(ws + 24576);
    const uint4*  w3f = (const uint4*)(ws + 40960);
    const float*  s1w = (const float*)(ws + 49152);
    const float*  t1w = (const float*)(ws + 49664);
    const float*  s2w = (const float*)(ws + 50176);
    const float*  t2w = (const float*)(ws + 50432);
    const float*  s3w = (const float*)(ws + 50688);
    const float*  t3w = (const float*)(ws + 50944);

    // ---- layer 1 A-fragments: consume ALL of X0 into registers ----
    short8v a1[3][3];
    #pragma unroll
    for (int k = 0; k < 3; ++k) {
        const int row = k * 64 + w * 16 + lo;
        a1[k][0] = *(const short8v*)&X0V(row, hi * 8);
        a1[k][1] = *(const short8v*)&X0V(row, 32 + hi * 8);
        FragU U; U.u.x = 0; U.u.y = 0; U.u.z = 0; U.u.w = 0;
        if (hi == 0) U.h[0] = *(const uint2*)&X0V(row, 64);
        a1[k][2] = U.s;
    }
    __syncthreads();   // B2: X0 dead, X1 region free

    // ---- layer 1 : K=96 (68 real) -> 128, write X1 ----
    #pragma unroll 2
    for (int ct = 0; ct < 8; ++ct) {
        FragU B0, B1, B2;
        B0.u = w1f[(ct * 3 + 0) * 64 + lane];
        B1.u = w1f[(ct * 3 + 1) * 64 + lane];
        B2.u = w1f[(ct * 3 + 2) * 64 + lane];
        const float sc = s1w[ct * 16 + lo];
        const float tb = t1w[ct * 16 + lo];
        #pragma unroll
        for (int k = 0; k < 3; ++k) {
            f32x4 acc = {0.f, 0.f, 0.f, 0.f};
            acc = __builtin_amdgcn_mfma_f32_16x16x32_bf16(a1[k][0], B0.s, acc, 0, 0, 0);
            acc = __builtin_amdgcn_mfma_f32_16x16x32_bf16(a1[k][1], B1.s, acc, 0, 0, 0);
            acc = __builtin_amdgcn_mfma_f32_16x16x32_bf16(a1[k][2], B2.s, acc, 0, 0, 0);
            const int rb = k * 64 + w * 16 + 4 * hi;
            #pragma unroll
            for (int j = 0; j < 4; ++j) {
                const float y = fmaxf(fmaf(sc, acc[j], tb), 0.f);
                X1V(rb + j, ct * 16 + lo) = f2bf(y);
            }
        }
    }

    // ---- layer 2 A-fragments: consume X1 (wave-private rows) ----
    short8v a2[3][4];
    #pragma unroll
    for (int k = 0; k < 3; ++k) {
        const int row = k * 64 + w * 16 + lo;
        #pragma unroll
        for (int ks = 0; ks < 4; ++ks)
            a2[k][ks] = *(const short8v*)&X1V(row, ks * 32 + hi * 8);
    }
    __syncthreads();   // B3: X1 dead

    // ---- layer 2 : K=128 -> 64, write X2 (X0 view) ----
    #pragma unroll 2
    for (int ct = 0; ct < 4; ++ct) {
        FragU B0, B1, B2, B3;
        B0.u = w2f[(ct * 4 + 0) * 64 + lane];
        B1.u = w2f[(ct * 4 + 1) * 64 + lane];
        B2.u = w2f[(ct * 4 + 2) * 64 + lane];
        B3.u = w2f[(ct * 4 + 3) * 64 + lane];
        const float sc = s2w[ct * 16 + lo];
        const float tb = t2w[ct * 16 + lo];
        #pragma unroll
        for (int k = 0; k < 3; ++k) {
            f32x4 acc = {0.f, 0.f, 0.f, 0.f};
            acc = __builtin_amdgcn_mfma_f32_16x16x32_bf16(a2[k][0], B0.s, acc, 0, 0, 0);
            acc = __builtin_amdgcn_mfma_f32_16x16x32_bf16(a2[k][1], B1.s, acc, 0, 0, 0);
            acc = __builtin_amdgcn_mfma_f32_16x16x32_bf16(a2[k][2], B2.s, acc, 0, 0, 0);
            acc = __builtin_amdgcn_mfma_f32_16x16x32_bf16(a2[k][3], B3.s, acc, 0, 0, 0);
            const int rb = k * 64 + w * 16 + 4 * hi;
            #pragma unroll
            for (int j = 0; j < 4; ++j) {
                const float y = fmaxf(fmaf(sc, acc[j], tb), 0.f);
                X0V(rb + j, ct * 16 + lo) = f2bf(y);
            }
        }
    }

    // ---- layer 3 : K=64 -> 64, BN+ReLU per k then register k-sum ----
    short8v a3[3][2];
    #pragma unroll
    for (int k = 0; k < 3; ++k) {
        const int row = k * 64 + w * 16 + lo;
        a3[k][0] = *(const short8v*)&X0V(row, hi * 8);
        a3[k][1] = *(const short8v*)&X0V(row, 32 + hi * 8);
    }
    #pragma unroll 2
    for (int ct = 0; ct < 4; ++ct) {
        FragU B0, B1;
        B0.u = w3f[(ct * 2 + 0) * 64 + lane];
        B1.u = w3f[(ct * 2 + 1) * 64 + lane];
        const float sc = s3w[ct * 16 + lo];
        const float tb = t3w[ct * 16 + lo];
        f32x4 acc0 = {0.f, 0.f, 0.f, 0.f};
        f32x4 acc1 = {0.f, 0.f, 0.f, 0.f};
        f32x4 acc2 = {0.f, 0.f, 0.f, 0.f};
        acc0 = __builtin_amdgcn_mfma_f32_16x16x32_bf16(a3[0][0], B0.s, acc0, 0, 0, 0);
        acc0 = __builtin_amdgcn_mfma_f32_16x16x32_bf16(a3[0][1], B1.s, acc0, 0, 0, 0);
        acc1 = __builtin_amdgcn_mfma_f32_16x16x32_bf16(a3[1][0], B0.s, acc1, 0, 0, 0);
        acc1 = __builtin_amdgcn_mfma_f32_16x16x32_bf16(a3[1][1], B1.s, acc1, 0, 0, 0);
        acc2 = __builtin_amdgcn_mfma_f32_16x16x32_bf16(a3[2][0], B0.s, acc2, 0, 0, 0);
        acc2 = __builtin_amdgcn_mfma_f32_16x16x32_bf16(a3[2][1], B1.s, acc2, 0, 0, 0);
        float4 r;
        float* rp4 = &r.x;
        #pragma unroll
        for (int j = 0; j < 4; ++j) {
            rp4[j] = fmaxf(fmaf(sc, acc0[j], tb), 0.f)
                   + fmaxf(fmaf(sc, acc1[j], tb), 0.f)
                   + fmaxf(fmaf(sc, acc2[j], tb), 0.f);
        }
        float* op = out + (size_t)(b * 64 + ct * 16 + lo) * N + n0 + w * 16 + 4 * hi;
        *(float4*)op = r;   // 4 lanes per o cover a full 64B line
    }
    #undef X0V
    #undef X1V
}

extern "C" void kernel_launch(void* const* d_in, const int* in_sizes, int n_in,
                              void* d_out, int out_size, void* d_ws, size_t ws_size,
                              hipStream_t stream)
{
    const float* src  = (const float*)d_in[0];
    const float* tgt  = (const float*)d_in[1];
    const float* feat = (const float*)d_in[2];
    const float* W1 = (const float*)d_in[3];
    const float* g1 = (const float*)d_in[4];
    const float* b1 = (const float*)d_in[5];
    const float* m1 = (const float*)d_in[6];
    const float* v1 = (const float*)d_in[7];
    const float* W2 = (const float*)d_in[8];
    const float* g2 = (const float*)d_in[9];
    const float* b2 = (const float*)d_in[10];
    const float* m2 = (const float*)d_in[11];
    const float* v2 = (const float*)d_in[12];
    const float* W3 = (const float*)d_in[13];
    const float* g3 = (const float*)d_in[14];
    const float* b3 = (const float*)d_in[15];
    const float* m3 = (const float*)d_in[16];
    const float* v3 = (const float*)d_in[17];
    float* out = (float*)d_out;
    char* ws = (char*)d_ws;

    hipLaunchKernelGGL(fa_pack, dim3(13), dim3(256), 0, stream,
                       W1, g1, b1, m1, v1, W2, g2, b2, m2, v2, W3, g3, b3, m3, v3, ws);
    hipLaunchKernelGGL(fa_mfma, dim3(8 * 256), dim3(256), 0, stream,
                       src, tgt, feat, ws, out);
}